// Round 1
// 1094.924 us; speedup vs baseline: 2.1873x; 2.1873x over previous
//
#include <hip/hip_runtime.h>
#include <cstdint>
#include <cstddef>

#define TT 4096
#define DM 1024
#define DN 2048
#define MROWS 16384  // B*T
#define NCH 16       // scan chunks per sequence
#define CHL 256      // chunk length (TT/NCH)
#define SW 16        // LDS staging window inside a chunk
#define XBCS 128     // xbc row stride (f32), padded from 96 for MFMA GEMM

typedef unsigned short u16;
typedef u16 ushort8_t __attribute__((ext_vector_type(8)));
typedef u16 ushort4_t __attribute__((ext_vector_type(4)));
typedef short bf16x8 __attribute__((ext_vector_type(8)));   // MFMA A/B frag (4 VGPR)
typedef float f32x4 __attribute__((ext_vector_type(4)));    // MFMA C/D frag

__device__ __forceinline__ float bf2f(u16 b) {
  return __uint_as_float(((unsigned int)b) << 16);
}
__device__ __forceinline__ u16 f2bf(float f) {
  unsigned int u = __float_as_uint(f);
  u = u + 0x7FFFu + ((u >> 16) & 1u);   // round-to-nearest-even
  return (u16)(u >> 16);
}

__device__ __forceinline__ void gload_lds16(const void* g, void* l) {
  __builtin_amdgcn_global_load_lds(
      (const __attribute__((address_space(1))) unsigned int*)g,
      (__attribute__((address_space(3))) unsigned int*)l, 16, 0, 0);
}

// ---------------- f32 -> bf16 converter (weights) ----------------
__global__ __launch_bounds__(256) void cvt_bf16_kernel(const float* __restrict__ in,
    u16* __restrict__ out, int n4) {
  int i = blockIdx.x * 256 + threadIdx.x;
  if (i >= n4) return;
  float4 v = ((const float4*)in)[i];
  ushort4_t o; o[0] = f2bf(v.x); o[1] = f2bf(v.y); o[2] = f2bf(v.z); o[3] = f2bf(v.w);
  ((ushort4_t*)out)[i] = o;
}

// ---------------- W_x f32(96x2048) -> bf16(128x2048), rows 96..127 zero ----------------
__global__ __launch_bounds__(256) void cvt_wx_kernel(const float* __restrict__ W_x,
    u16* __restrict__ out) {
  int i = blockIdx.x * 256 + threadIdx.x;   // over 128*2048/4 = 65536 float4 slots
  int row = i >> 9;                         // 512 float4 per row
  ushort4_t o;
  if (row < 96) {
    float4 v = ((const float4*)W_x)[i];
    o[0] = f2bf(v.x); o[1] = f2bf(v.y); o[2] = f2bf(v.z); o[3] = f2bf(v.w);
  } else {
    o[0] = 0; o[1] = 0; o[2] = 0; o[3] = 0;
  }
  ((ushort4_t*)out)[i] = o;
}

// ---------------- LayerNorm -> bf16 out ----------------
__global__ __launch_bounds__(256) void ln_kernel(const float* __restrict__ x,
    const float* __restrict__ ln_w, const float* __restrict__ ln_b,
    u16* __restrict__ xn) {
  int row = blockIdx.x;
  int tid = threadIdx.x;
  const float4* xr = (const float4*)(x + (size_t)row * DM);
  float4 v = xr[tid];
  float s  = v.x + v.y + v.z + v.w;
  float s2 = v.x*v.x + v.y*v.y + v.z*v.z + v.w*v.w;
#pragma unroll
  for (int o = 32; o > 0; o >>= 1) { s += __shfl_down(s, o, 64); s2 += __shfl_down(s2, o, 64); }
  __shared__ float red[2][4];
  __shared__ float mv[2];
  int wid = tid >> 6, lane = tid & 63;
  if (lane == 0) { red[0][wid] = s; red[1][wid] = s2; }
  __syncthreads();
  if (tid == 0) {
    float a  = red[0][0] + red[0][1] + red[0][2] + red[0][3];
    float b2 = red[1][0] + red[1][1] + red[1][2] + red[1][3];
    float mean = a * (1.f / DM);
    float var  = b2 * (1.f / DM) - mean * mean;
    mv[0] = mean; mv[1] = rsqrtf(var + 1e-5f);
  }
  __syncthreads();
  float mean = mv[0], inv = mv[1];
  float4 w = ((const float4*)ln_w)[tid];
  float4 b = ((const float4*)ln_b)[tid];
  ushort4_t o;
  o[0] = f2bf((v.x - mean) * inv * w.x + b.x);
  o[1] = f2bf((v.y - mean) * inv * w.y + b.y);
  o[2] = f2bf((v.z - mean) * inv * w.z + b.z);
  o[3] = f2bf((v.w - mean) * inv * w.w + b.w);
  *(ushort4_t*)(xn + (size_t)row * DM + tid * 4) = o;
}

// ---------------- bf16 MFMA GEMM, NT: C[i][j] = sum_k A[i][k]*B[j][k] (+Res) -----------
// 128x128 tile, BK=64, 256 thr (4 waves 2x2), per wave 4x4 frags of 16x16x32.
// LDS tiles [128][64] bf16, XOR-swizzled: phys_colbyte = logical_colbyte ^ ((row&7)<<4),
// staged via global_load_lds with inverse-swizzled per-lane global source (both-sides rule).
template<bool CBF16, bool RES>
__global__ __launch_bounds__(256) void gemm_mfma_nt(
    const u16* __restrict__ A, int lda,
    const u16* __restrict__ B, int ldb,
    void* __restrict__ Cp, int ldc,
    const float* __restrict__ Res, int K) {
  __shared__ __align__(16) u16 a_s[128 * 64];
  __shared__ __align__(16) u16 b_s[128 * 64];
  const int tid = threadIdx.x;
  const int w = tid >> 6, l = tid & 63;
  const int wr = w >> 1, wc = w & 1;
  const int bi = blockIdx.x, bj = blockIdx.y;
  const int lrow = l >> 3;                    // lane's row-in-8 within a 1KB chunk
  const int scol = ((l & 7) ^ lrow) * 16;     // inverse-swizzled source byte-in-row

  f32x4 acc[4][4] = {};

  const u16* Abase = A + (size_t)(bi * 128 + w * 8 + lrow) * lda;
  const u16* Bbase = B + (size_t)(bj * 128 + w * 8 + lrow) * ldb;

  for (int k0 = 0; k0 < K; k0 += 64) {
#pragma unroll
    for (int c = 0; c < 4; c++) {
      const char* ga = (const char*)(Abase + (size_t)(c * 32) * lda + k0) + scol;
      const char* gb = (const char*)(Bbase + (size_t)(c * 32) * ldb + k0) + scol;
      gload_lds16(ga, (char*)a_s + c * 4096 + w * 1024);
      gload_lds16(gb, (char*)b_s + c * 4096 + w * 1024);
    }
    __syncthreads();   // drains vmcnt before barrier (compiler-enforced)
#pragma unroll
    for (int kk = 0; kk < 2; kk++) {
      bf16x8 af[4], bfr[4];
#pragma unroll
      for (int m = 0; m < 4; m++) {
        int fr = wr * 64 + m * 16 + (l & 15);
        int cb = (kk * 64 + ((l >> 4) << 4)) ^ ((fr & 7) << 4);
        af[m] = *(const bf16x8*)((const char*)a_s + fr * 128 + cb);
      }
#pragma unroll
      for (int n = 0; n < 4; n++) {
        int fr = wc * 64 + n * 16 + (l & 15);
        int cb = (kk * 64 + ((l >> 4) << 4)) ^ ((fr & 7) << 4);
        bfr[n] = *(const bf16x8*)((const char*)b_s + fr * 128 + cb);
      }
#pragma unroll
      for (int m = 0; m < 4; m++)
#pragma unroll
        for (int n = 0; n < 4; n++)
          acc[m][n] = __builtin_amdgcn_mfma_f32_16x16x32_bf16(af[m], bfr[n], acc[m][n], 0, 0, 0);
    }
    __syncthreads();
  }
  // epilogue: C/D layout col = l&15, row = (l>>4)*4 + reg (m89-verified)
  const int col0 = bj * 128 + wc * 64 + (l & 15);
  const int row0 = bi * 128 + wr * 64 + (l >> 4) * 4;
#pragma unroll
  for (int m = 0; m < 4; m++)
#pragma unroll
    for (int n = 0; n < 4; n++) {
#pragma unroll
      for (int r = 0; r < 4; r++) {
        size_t row = (size_t)(row0 + m * 16 + r);
        size_t col = (size_t)(col0 + n * 16);
        float v = acc[m][n][r];
        if constexpr (CBF16) {
          ((u16*)Cp)[row * ldc + col] = f2bf(v);
        } else {
          if constexpr (RES) v += Res[row * ldc + col];
          ((float*)Cp)[row * ldc + col] = v;
        }
      }
    }
}

// ---------------- causal depthwise conv (width 4) + SiLU; bf16 in, bf16 out ----------------
__global__ __launch_bounds__(256) void conv_silu_kernel(const u16* __restrict__ xz,
    const float* __restrict__ conv_w, const float* __restrict__ conv_b,
    u16* __restrict__ u) {
  size_t gid = (size_t)blockIdx.x * 256 + threadIdx.x;
  int c = (int)(gid & 255);
  size_t i = gid >> 8;
  int t = (int)(i & (TT - 1));
  int d0 = c * 8;
  const u16* base = xz + i * 4096 + d0;
  ushort8_t r0 = *(const ushort8_t*)base;
  ushort8_t r1 = 0, r2 = 0, r3 = 0;
  if (t >= 1) r1 = *(const ushort8_t*)(base - 4096);
  if (t >= 2) r2 = *(const ushort8_t*)(base - 2 * 4096);
  if (t >= 3) r3 = *(const ushort8_t*)(base - 3 * 4096);
  float cbv[8];
  *(float4*)&cbv[0] = *(const float4*)(conv_b + d0);
  *(float4*)&cbv[4] = *(const float4*)(conv_b + d0 + 4);
  ushort8_t o;
#pragma unroll
  for (int j = 0; j < 8; j++) {
    float4 w = *(const float4*)(conv_w + (size_t)(d0 + j) * 4);
    float a = cbv[j] + w.w * bf2f(r0[j]) + w.z * bf2f(r1[j])
            + w.y * bf2f(r2[j]) + w.x * bf2f(r3[j]);
    a = a / (1.f + __expf(-a));
    o[j] = f2bf(a);
  }
  *(ushort8_t*)(u + i * 2048 + d0) = o;
}

// ---------------- scan phase 1: local chunk scans from h=0 -> h_end, sum(dt) ----------------
__global__ __launch_bounds__(256) void scan_part1(const u16* __restrict__ u,
    const float* __restrict__ xbc, const float* __restrict__ W_dt,
    const float* __restrict__ b_dt, const float* __restrict__ log_A,
    float* __restrict__ hbuf, float* __restrict__ Sbuf) {
  int d0 = blockIdx.x * 256;
  int c  = blockIdx.y;
  int b  = blockIdx.z;
  int tid = threadIdx.x;
  int d = d0 + tid;
  __shared__ __align__(16) float u_s[SW][256];
  __shared__ __align__(16) float dl_s[SW][64];
  __shared__ float bs_s[SW][16];
  float wdt[64];
#pragma unroll
  for (int k = 0; k < 64; k += 4)
    *(float4*)&wdt[k] = *(const float4*)(W_dt + (size_t)d * 64 + k);
  float bA = b_dt[d];
  float A[16];
#pragma unroll
  for (int n = 0; n < 16; n++) A[n] = -__expf(log_A[(size_t)d * 16 + n]);
  float h[16] = {};
  float sdt = 0.f;
  size_t t0 = (size_t)b * TT + (size_t)c * CHL;
  for (int wnd = 0; wnd < CHL / SW; wnd++) {
    size_t i0 = t0 + (size_t)wnd * SW;
#pragma unroll
    for (int lq = 0; lq < 4; lq++) {
      int idx = tid + lq * 256;    // float4 slot over SW*64
      int tt = idx >> 6, q = idx & 63;
      ushort4_t v = *(const ushort4_t*)(u + (i0 + tt) * 2048 + d0 + q * 4);
      float4 f; f.x = bf2f(v[0]); f.y = bf2f(v[1]); f.z = bf2f(v[2]); f.w = bf2f(v[3]);
      *(float4*)&u_s[tt][q * 4] = f;
    }
    {
      int tt = tid >> 4, q = tid & 15;
      *(float4*)&dl_s[tt][q * 4] = *(const float4*)(xbc + (i0 + tt) * XBCS + q * 4);
      bs_s[tt][q] = xbc[(i0 + tt) * XBCS + 64 + q];
    }
    __syncthreads();
    for (int tt = 0; tt < SW; tt++) {
      float s0 = bA, s1 = 0.f, s2 = 0.f, s3 = 0.f;
#pragma unroll
      for (int k = 0; k < 64; k += 4) {
        s0 += dl_s[tt][k]     * wdt[k];
        s1 += dl_s[tt][k + 1] * wdt[k + 1];
        s2 += dl_s[tt][k + 2] * wdt[k + 2];
        s3 += dl_s[tt][k + 3] * wdt[k + 3];
      }
      float s = (s0 + s1) + (s2 + s3);
      float sp = (s > 20.f) ? s : log1pf(__expf(s));
      float dtv = fminf(fmaxf(sp + 1e-3f, 1e-3f), 0.1f);
      sdt += dtv;
      float xin = dtv * u_s[tt][tid];
#pragma unroll
      for (int n = 0; n < 16; n++)
        h[n] = __expf(dtv * A[n]) * h[n] + xin * bs_s[tt][n];
    }
    __syncthreads();
  }
  float* hp = hbuf + ((((size_t)b * NCH + c) * DN) + d) * 16;
#pragma unroll
  for (int n = 0; n < 16; n++) hp[n] = h[n];
  Sbuf[((size_t)b * NCH + c) * DN + d] = sdt;
}

// ---------------- scan phase 2: sequential chunk combine (in-place h_end -> h_start) -------
__global__ __launch_bounds__(256) void scan_combine(const float* __restrict__ log_A,
    const float* __restrict__ Sbuf, float* __restrict__ hbuf) {
  int idx = blockIdx.x * 256 + threadIdx.x;    // over B*DN*16
  int n = idx & 15, d = (idx >> 4) & (DN - 1), b = idx >> 15;
  float A = -__expf(log_A[(size_t)d * 16 + n]);
  float h = 0.f;
#pragma unroll
  for (int c = 0; c < NCH; c++) {
    size_t off = (((size_t)b * NCH + c) * DN + d) * 16 + n;
    float hl = hbuf[off];
    float P = __expf(A * Sbuf[((size_t)b * NCH + c) * DN + d]);
    hbuf[off] = h;                 // now holds h_start for chunk c
    h = hl + P * h;
  }
}

// ---------------- scan phase 3: re-scan with h_start, D skip + SiLU(z) gate, y over u ------
__global__ __launch_bounds__(256) void scan_part2(const u16* u,
    const u16* __restrict__ xz, const float* __restrict__ xbc,
    const float* __restrict__ W_dt, const float* __restrict__ b_dt,
    const float* __restrict__ log_A, const float* __restrict__ D_param,
    const float* __restrict__ hbuf, u16* y) {
  int d0 = blockIdx.x * 256;
  int c  = blockIdx.y;
  int b  = blockIdx.z;
  int tid = threadIdx.x;
  int d = d0 + tid;
  __shared__ __align__(16) float u_s[SW][256];
  __shared__ __align__(16) float z_s[SW][256];
  __shared__ __align__(16) float dl_s[SW][64];
  __shared__ float bc_s[SW][32];
  float wdt[64];
#pragma unroll
  for (int k = 0; k < 64; k += 4)
    *(float4*)&wdt[k] = *(const float4*)(W_dt + (size_t)d * 64 + k);
  float bA = b_dt[d];
  float A[16];
#pragma unroll
  for (int n = 0; n < 16; n++) A[n] = -__expf(log_A[(size_t)d * 16 + n]);
  float Dp = D_param[d];
  float h[16];
  const float* hp = hbuf + ((((size_t)b * NCH + c) * DN) + d) * 16;
#pragma unroll
  for (int n = 0; n < 16; n++) h[n] = hp[n];
  size_t t0 = (size_t)b * TT + (size_t)c * CHL;
  for (int wnd = 0; wnd < CHL / SW; wnd++) {
    size_t i0 = t0 + (size_t)wnd * SW;
#pragma unroll
    for (int lq = 0; lq < 4; lq++) {
      int idx = tid + lq * 256;
      int tt = idx >> 6, q = idx & 63;
      ushort4_t vu = *(const ushort4_t*)(u  + (i0 + tt) * 2048 + d0 + q * 4);
      ushort4_t vz = *(const ushort4_t*)(xz + (i0 + tt) * 4096 + 2048 + d0 + q * 4);
      float4 fu; fu.x = bf2f(vu[0]); fu.y = bf2f(vu[1]); fu.z = bf2f(vu[2]); fu.w = bf2f(vu[3]);
      float4 fz; fz.x = bf2f(vz[0]); fz.y = bf2f(vz[1]); fz.z = bf2f(vz[2]); fz.w = bf2f(vz[3]);
      *(float4*)&u_s[tt][q * 4] = fu;
      *(float4*)&z_s[tt][q * 4] = fz;
    }
    {
      int tt = tid >> 4, q = tid & 15;
      *(float4*)&dl_s[tt][q * 4] = *(const float4*)(xbc + (i0 + tt) * XBCS + q * 4);
      bc_s[tid >> 5][tid & 31] = xbc[(i0 + (tid >> 5)) * XBCS + 64 + (tid & 31)];
      int idx2 = tid + 256;
      bc_s[idx2 >> 5][idx2 & 31] = xbc[(i0 + (idx2 >> 5)) * XBCS + 64 + (idx2 & 31)];
    }
    __syncthreads();
    for (int tt = 0; tt < SW; tt++) {
      float s0 = bA, s1 = 0.f, s2 = 0.f, s3 = 0.f;
#pragma unroll
      for (int k = 0; k < 64; k += 4) {
        s0 += dl_s[tt][k]     * wdt[k];
        s1 += dl_s[tt][k + 1] * wdt[k + 1];
        s2 += dl_s[tt][k + 2] * wdt[k + 2];
        s3 += dl_s[tt][k + 3] * wdt[k + 3];
      }
      float s = (s0 + s1) + (s2 + s3);
      float sp = (s > 20.f) ? s : log1pf(__expf(s));
      float dtv = fminf(fmaxf(sp + 1e-3f, 1e-3f), 0.1f);
      float uv = u_s[tt][tid], zv = z_s[tt][tid];
      float xin = dtv * uv;
      float yv = 0.f;
#pragma unroll
      for (int n = 0; n < 16; n++) {
        h[n] = __expf(dtv * A[n]) * h[n] + xin * bc_s[tt][n];
        yv += h[n] * bc_s[tt][16 + n];
      }
      yv += uv * Dp;
      yv *= zv / (1.f + __expf(-zv));
      y[(i0 + tt) * 2048 + d] = f2bf(yv);
    }
    __syncthreads();
  }
}

extern "C" void kernel_launch(void* const* d_in, const int* in_sizes, int n_in,
                              void* d_out, int out_size, void* d_ws, size_t ws_size,
                              hipStream_t stream) {
  const float* x       = (const float*)d_in[0];
  const float* W_in    = (const float*)d_in[1];
  const float* conv_w  = (const float*)d_in[2];
  const float* conv_b  = (const float*)d_in[3];
  const float* W_x     = (const float*)d_in[4];
  const float* W_dt    = (const float*)d_in[5];
  const float* b_dt    = (const float*)d_in[6];
  const float* log_A   = (const float*)d_in[7];
  const float* D_param = (const float*)d_in[8];
  const float* W_out   = (const float*)d_in[9];
  const float* ln_w    = (const float*)d_in[10];
  const float* ln_b    = (const float*)d_in[11];
  float* out = (float*)d_out;

  // ws (proven >=198MiB): xz 128MiB + u 64MiB + 6MiB tail (W_out bf16 staging)
  size_t need = (size_t)MROWS * 4096 * 2 + (size_t)MROWS * DN * 2 + (size_t)MROWS * 96 * 4;
  if (ws_size < need) return;
  u16*   xz  = (u16*)d_ws;                        // 16384 x 4096 bf16 (x_inner | z)
  u16*   u   = xz + (size_t)MROWS * 4096;         // 16384 x 2048 bf16 (y overwrites in place)
  u16*   W_out_b = (u16*)(u + (size_t)MROWS * DN);// 4MiB, used only for gemm2 staging

  // d_out (64MiB) staging: all dead before gemm2 fully overwrites d_out
  u16*   xn_b    = (u16*)d_out;                                  // [0,32)MiB, dead after gemm1
  float* xbc     = (float*)d_out;                                // [0,8)MiB, written AFTER gemm1
  u16*   W_in_b  = (u16*)((char*)d_out + (32u << 20));           // [32,40)MiB
  float* hbuf    = (float*)((char*)d_out + (40u << 20));         // [40,48)MiB
  float* Sbuf    = (float*)((char*)d_out + (48u << 20));         // [48,48.5)MiB
  u16*   W_x_b   = (u16*)((char*)d_out + (48u << 20) + (512u << 10)); // [48.5,49)MiB, 128x2048 bf16

  cvt_wx_kernel<<<(128 * 2048 / 4) / 256, 256, 0, stream>>>(W_x, W_x_b);
  ln_kernel<<<MROWS, 256, 0, stream>>>(x, ln_w, ln_b, xn_b);
  cvt_bf16_kernel<<<(4096 * 1024 / 4) / 256, 256, 0, stream>>>(W_in, W_in_b, 4096 * 1024 / 4);
  gemm_mfma_nt<true, false><<<dim3(MROWS / 128, 4096 / 128), 256, 0, stream>>>(
      xn_b, DM, W_in_b, DM, xz, 4096, nullptr, DM);
  conv_silu_kernel<<<MROWS, 256, 0, stream>>>(xz, conv_w, conv_b, u);
  // xbc = u @ W_x.T via MFMA (N padded 96->128, pad cols are zeros); overwrites dead xn_b
  gemm_mfma_nt<false, false><<<dim3(MROWS / 128, XBCS / 128), 256, 0, stream>>>(
      u, DN, W_x_b, DN, xbc, XBCS, nullptr, DN);
  scan_part1<<<dim3(DN / 256, NCH, 4), 256, 0, stream>>>(
      u, xbc, W_dt, b_dt, log_A, hbuf, Sbuf);
  scan_combine<<<4 * DN * 16 / 256, 256, 0, stream>>>(log_A, Sbuf, hbuf);
  scan_part2<<<dim3(DN / 256, NCH, 4), 256, 0, stream>>>(
      u, xz, xbc, W_dt, b_dt, log_A, D_param, hbuf, u);
  cvt_bf16_kernel<<<(1024 * 2048 / 4) / 256, 256, 0, stream>>>(W_out, W_out_b, 1024 * 2048 / 4);
  gemm_mfma_nt<false, true><<<dim3(MROWS / 128, 1024 / 128), 256, 0, stream>>>(
      u, DN, W_out_b, DN, out, DM, x, DN);
}

// Round 2
// 980.425 us; speedup vs baseline: 2.4427x; 1.1168x over previous
//
#include <hip/hip_runtime.h>
#include <cstdint>
#include <cstddef>

#define TT 4096
#define DM 1024
#define DN 2048
#define MROWS 16384  // B*T
#define NCH 32       // scan chunks per sequence
#define CHL 128      // chunk length (TT/NCH)
#define SW 16        // LDS staging window inside a chunk
#define XBCS 128     // xbc row stride (f32), padded from 96 for MFMA GEMM

typedef unsigned short u16;
typedef u16 ushort8_t __attribute__((ext_vector_type(8)));
typedef u16 ushort4_t __attribute__((ext_vector_type(4)));
typedef short bf16x8 __attribute__((ext_vector_type(8)));   // MFMA A/B frag (4 VGPR)
typedef float f32x4 __attribute__((ext_vector_type(4)));    // MFMA C/D frag

__device__ __forceinline__ float bf2f(u16 b) {
  return __uint_as_float(((unsigned int)b) << 16);
}
__device__ __forceinline__ u16 f2bf(float f) {
  unsigned int u = __float_as_uint(f);
  u = u + 0x7FFFu + ((u >> 16) & 1u);   // round-to-nearest-even
  return (u16)(u >> 16);
}

__device__ __forceinline__ void gload_lds16(const void* g, void* l) {
  __builtin_amdgcn_global_load_lds(
      (const __attribute__((address_space(1))) unsigned int*)g,
      (__attribute__((address_space(3))) unsigned int*)l, 16, 0, 0);
}

// ---------------- f32 -> bf16 converter (weights) ----------------
__global__ __launch_bounds__(256) void cvt_bf16_kernel(const float* __restrict__ in,
    u16* __restrict__ out, int n4) {
  int i = blockIdx.x * 256 + threadIdx.x;
  if (i >= n4) return;
  float4 v = ((const float4*)in)[i];
  ushort4_t o; o[0] = f2bf(v.x); o[1] = f2bf(v.y); o[2] = f2bf(v.z); o[3] = f2bf(v.w);
  ((ushort4_t*)out)[i] = o;
}

// ---------------- W_x f32(96x2048) -> bf16(128x2048), rows 96..127 zero ----------------
__global__ __launch_bounds__(256) void cvt_wx_kernel(const float* __restrict__ W_x,
    u16* __restrict__ out) {
  int i = blockIdx.x * 256 + threadIdx.x;   // over 128*2048/4 = 65536 float4 slots
  int row = i >> 9;                         // 512 float4 per row
  ushort4_t o;
  if (row < 96) {
    float4 v = ((const float4*)W_x)[i];
    o[0] = f2bf(v.x); o[1] = f2bf(v.y); o[2] = f2bf(v.z); o[3] = f2bf(v.w);
  } else {
    o[0] = 0; o[1] = 0; o[2] = 0; o[3] = 0;
  }
  ((ushort4_t*)out)[i] = o;
}

// ---------------- LayerNorm -> bf16 out ----------------
__global__ __launch_bounds__(256) void ln_kernel(const float* __restrict__ x,
    const float* __restrict__ ln_w, const float* __restrict__ ln_b,
    u16* __restrict__ xn) {
  int row = blockIdx.x;
  int tid = threadIdx.x;
  const float4* xr = (const float4*)(x + (size_t)row * DM);
  float4 v = xr[tid];
  float s  = v.x + v.y + v.z + v.w;
  float s2 = v.x*v.x + v.y*v.y + v.z*v.z + v.w*v.w;
#pragma unroll
  for (int o = 32; o > 0; o >>= 1) { s += __shfl_down(s, o, 64); s2 += __shfl_down(s2, o, 64); }
  __shared__ float red[2][4];
  __shared__ float mv[2];
  int wid = tid >> 6, lane = tid & 63;
  if (lane == 0) { red[0][wid] = s; red[1][wid] = s2; }
  __syncthreads();
  if (tid == 0) {
    float a  = red[0][0] + red[0][1] + red[0][2] + red[0][3];
    float b2 = red[1][0] + red[1][1] + red[1][2] + red[1][3];
    float mean = a * (1.f / DM);
    float var  = b2 * (1.f / DM) - mean * mean;
    mv[0] = mean; mv[1] = rsqrtf(var + 1e-5f);
  }
  __syncthreads();
  float mean = mv[0], inv = mv[1];
  float4 w = ((const float4*)ln_w)[tid];
  float4 b = ((const float4*)ln_b)[tid];
  ushort4_t o;
  o[0] = f2bf((v.x - mean) * inv * w.x + b.x);
  o[1] = f2bf((v.y - mean) * inv * w.y + b.y);
  o[2] = f2bf((v.z - mean) * inv * w.z + b.z);
  o[3] = f2bf((v.w - mean) * inv * w.w + b.w);
  *(ushort4_t*)(xn + (size_t)row * DM + tid * 4) = o;
}

// ---------------- bf16 MFMA GEMM, NT: C[i][j] = sum_k A[i][k]*B[j][k] (+Res) -----------
template<bool CBF16, bool RES>
__global__ __launch_bounds__(256) void gemm_mfma_nt(
    const u16* __restrict__ A, int lda,
    const u16* __restrict__ B, int ldb,
    void* __restrict__ Cp, int ldc,
    const float* __restrict__ Res, int K) {
  __shared__ __align__(16) u16 a_s[128 * 64];
  __shared__ __align__(16) u16 b_s[128 * 64];
  const int tid = threadIdx.x;
  const int w = tid >> 6, l = tid & 63;
  const int wr = w >> 1, wc = w & 1;
  const int bi = blockIdx.x, bj = blockIdx.y;
  const int lrow = l >> 3;                    // lane's row-in-8 within a 1KB chunk
  const int scol = ((l & 7) ^ lrow) * 16;     // inverse-swizzled source byte-in-row

  f32x4 acc[4][4] = {};

  const u16* Abase = A + (size_t)(bi * 128 + w * 8 + lrow) * lda;
  const u16* Bbase = B + (size_t)(bj * 128 + w * 8 + lrow) * ldb;

  for (int k0 = 0; k0 < K; k0 += 64) {
#pragma unroll
    for (int c = 0; c < 4; c++) {
      const char* ga = (const char*)(Abase + (size_t)(c * 32) * lda + k0) + scol;
      const char* gb = (const char*)(Bbase + (size_t)(c * 32) * ldb + k0) + scol;
      gload_lds16(ga, (char*)a_s + c * 4096 + w * 1024);
      gload_lds16(gb, (char*)b_s + c * 4096 + w * 1024);
    }
    __syncthreads();
#pragma unroll
    for (int kk = 0; kk < 2; kk++) {
      bf16x8 af[4], bfr[4];
#pragma unroll
      for (int m = 0; m < 4; m++) {
        int fr = wr * 64 + m * 16 + (l & 15);
        int cb = (kk * 64 + ((l >> 4) << 4)) ^ ((fr & 7) << 4);
        af[m] = *(const bf16x8*)((const char*)a_s + fr * 128 + cb);
      }
#pragma unroll
      for (int n = 0; n < 4; n++) {
        int fr = wc * 64 + n * 16 + (l & 15);
        int cb = (kk * 64 + ((l >> 4) << 4)) ^ ((fr & 7) << 4);
        bfr[n] = *(const bf16x8*)((const char*)b_s + fr * 128 + cb);
      }
#pragma unroll
      for (int m = 0; m < 4; m++)
#pragma unroll
        for (int n = 0; n < 4; n++)
          acc[m][n] = __builtin_amdgcn_mfma_f32_16x16x32_bf16(af[m], bfr[n], acc[m][n], 0, 0, 0);
    }
    __syncthreads();
  }
  const int col0 = bj * 128 + wc * 64 + (l & 15);
  const int row0 = bi * 128 + wr * 64 + (l >> 4) * 4;
#pragma unroll
  for (int m = 0; m < 4; m++)
#pragma unroll
    for (int n = 0; n < 4; n++) {
#pragma unroll
      for (int r = 0; r < 4; r++) {
        size_t row = (size_t)(row0 + m * 16 + r);
        size_t col = (size_t)(col0 + n * 16);
        float v = acc[m][n][r];
        if constexpr (CBF16) {
          ((u16*)Cp)[row * ldc + col] = f2bf(v);
        } else {
          if constexpr (RES) v += Res[row * ldc + col];
          ((float*)Cp)[row * ldc + col] = v;
        }
      }
    }
}

// ---------------- causal depthwise conv (width 4) + SiLU; bf16 in, bf16 out ----------------
__global__ __launch_bounds__(256) void conv_silu_kernel(const u16* __restrict__ xz,
    const float* __restrict__ conv_w, const float* __restrict__ conv_b,
    u16* __restrict__ u) {
  size_t gid = (size_t)blockIdx.x * 256 + threadIdx.x;
  int c = (int)(gid & 255);
  size_t i = gid >> 8;
  int t = (int)(i & (TT - 1));
  int d0 = c * 8;
  const u16* base = xz + i * 4096 + d0;
  ushort8_t r0 = *(const ushort8_t*)base;
  ushort8_t r1 = 0, r2 = 0, r3 = 0;
  if (t >= 1) r1 = *(const ushort8_t*)(base - 4096);
  if (t >= 2) r2 = *(const ushort8_t*)(base - 2 * 4096);
  if (t >= 3) r3 = *(const ushort8_t*)(base - 3 * 4096);
  float cbv[8];
  *(float4*)&cbv[0] = *(const float4*)(conv_b + d0);
  *(float4*)&cbv[4] = *(const float4*)(conv_b + d0 + 4);
  ushort8_t o;
#pragma unroll
  for (int j = 0; j < 8; j++) {
    float4 w = *(const float4*)(conv_w + (size_t)(d0 + j) * 4);
    float a = cbv[j] + w.w * bf2f(r0[j]) + w.z * bf2f(r1[j])
            + w.y * bf2f(r2[j]) + w.x * bf2f(r3[j]);
    a = a / (1.f + __expf(-a));
    o[j] = f2bf(a);
  }
  *(ushort8_t*)(u + i * 2048 + d0) = o;
}

// ---------------- scan phase 1: local chunk scans from h=0 -> h_end, sum(dt) ----------------
// dt = softplus(dl @ W_dt_blk^T + b) computed per 16-t window via MFMA (16x256x64),
// W_dt block (256x64) preloaded as bf16 register fragments once per block.
__global__ __launch_bounds__(256) void scan_part1(const u16* __restrict__ u,
    const float* __restrict__ xbc, const float* __restrict__ W_dt,
    const float* __restrict__ b_dt, const float* __restrict__ log_A,
    float* __restrict__ hbuf, float* __restrict__ Sbuf) {
  int d0 = blockIdx.x * 256;
  int c  = blockIdx.y;
  int b  = blockIdx.z;
  int tid = threadIdx.x;
  int w = tid >> 6, l = tid & 63;
  int d = d0 + tid;
  __shared__ __align__(16) char smem[32768];
  u16* wdtb = (u16*)smem;                              // [0,32K) one-time
  u16 (*u_s)[256] = (u16(*)[256])smem;                 // [0,8K)
  u16* dl_s = (u16*)(smem + 8192);                     // [8K,10K)
  float (*dt_s)[256] = (float(*)[256])(smem + 10240);  // [10K,26K)
  float (*bs_s)[16] = (float(*)[16])(smem + 26624);    // [26K,27K)

  // one-time: W_dt block -> bf16 swizzled LDS -> register B-frags
  for (int it = tid; it < 4096; it += 256) {
    int row = it >> 4, c4 = it & 15;
    float4 v = *(const float4*)(W_dt + (size_t)(d0 + row) * 64 + c4 * 4);
    ushort4_t o; o[0] = f2bf(v.x); o[1] = f2bf(v.y); o[2] = f2bf(v.z); o[3] = f2bf(v.w);
    *(ushort4_t*)((char*)wdtb + row * 128 + ((c4 * 8) ^ ((row & 7) << 4))) = o;
  }
  __syncthreads();
  bf16x8 wf[4][2];
  float bvals[4];
#pragma unroll
  for (int n = 0; n < 4; n++) {
    int row = w * 64 + n * 16 + (l & 15);
    bvals[n] = b_dt[d0 + row];
#pragma unroll
    for (int kk = 0; kk < 2; kk++) {
      int cb = (kk * 64 + ((l >> 4) << 4)) ^ ((row & 7) << 4);
      wf[n][kk] = *(const bf16x8*)((const char*)wdtb + row * 128 + cb);
    }
  }
  __syncthreads();

  float A2[16];
#pragma unroll
  for (int n = 0; n < 16; n++)
    A2[n] = -__expf(log_A[(size_t)d * 16 + n]) * 1.44269504f;
  float h[16] = {};
  float sdt = 0.f;
  size_t t0 = (size_t)b * TT + (size_t)c * CHL;
  for (int wnd = 0; wnd < CHL / SW; wnd++) {
    size_t i0 = t0 + (size_t)wnd * SW;
#pragma unroll
    for (int lq = 0; lq < 2; lq++) {
      int idx = tid + lq * 256;
      int tt = idx >> 5, q = (idx & 31) * 8;
      *(ushort8_t*)&u_s[tt][q] = *(const ushort8_t*)(u + (i0 + tt) * 2048 + d0 + q);
    }
    {
      int row = tid >> 4, c4 = tid & 15;
      float4 v = *(const float4*)(xbc + (i0 + row) * XBCS + c4 * 4);
      ushort4_t o; o[0] = f2bf(v.x); o[1] = f2bf(v.y); o[2] = f2bf(v.z); o[3] = f2bf(v.w);
      *(ushort4_t*)((char*)dl_s + row * 128 + ((c4 * 8) ^ ((row & 7) << 4))) = o;
      bs_s[row][c4] = xbc[(i0 + row) * XBCS + 64 + c4];
    }
    __syncthreads();
    // dt = softplus(MFMA) per window
    f32x4 dacc[4] = {};
    bf16x8 afr[2];
#pragma unroll
    for (int kk = 0; kk < 2; kk++) {
      int row = l & 15;
      int cb = (kk * 64 + ((l >> 4) << 4)) ^ ((row & 7) << 4);
      afr[kk] = *(const bf16x8*)((const char*)dl_s + row * 128 + cb);
    }
#pragma unroll
    for (int n = 0; n < 4; n++)
#pragma unroll
      for (int kk = 0; kk < 2; kk++)
        dacc[n] = __builtin_amdgcn_mfma_f32_16x16x32_bf16(afr[kk], wf[n][kk], dacc[n], 0, 0, 0);
#pragma unroll
    for (int n = 0; n < 4; n++) {
      int dcol = w * 64 + n * 16 + (l & 15);
#pragma unroll
      for (int r = 0; r < 4; r++) {
        float s = dacc[n][r] + bvals[n];
        float sp = (s > 20.f) ? s : log1pf(__expf(s));
        dt_s[(l >> 4) * 4 + r][dcol] = fminf(fmaxf(sp + 1e-3f, 1e-3f), 0.1f);
      }
    }
    __syncthreads();
    for (int tt = 0; tt < SW; tt++) {
      float dtv = dt_s[tt][tid];
      sdt += dtv;
      float xin = dtv * bf2f(u_s[tt][tid]);
#pragma unroll
      for (int n = 0; n < 16; n++)
        h[n] = exp2f(dtv * A2[n]) * h[n] + xin * bs_s[tt][n];
    }
    __syncthreads();
  }
  float* hp = hbuf + ((((size_t)b * NCH + c) * DN) + d) * 16;
#pragma unroll
  for (int n = 0; n < 16; n++) hp[n] = h[n];
  Sbuf[((size_t)b * NCH + c) * DN + d] = sdt;
}

// ---------------- scan phase 2: sequential chunk combine (in-place h_end -> h_start) -------
__global__ __launch_bounds__(256) void scan_combine(const float* __restrict__ log_A,
    const float* __restrict__ Sbuf, float* __restrict__ hbuf) {
  int idx = blockIdx.x * 256 + threadIdx.x;    // over B*DN*16
  int n = idx & 15, d = (idx >> 4) & (DN - 1), b = idx >> 15;
  float A = -__expf(log_A[(size_t)d * 16 + n]);
  float h = 0.f;
#pragma unroll
  for (int c = 0; c < NCH; c++) {
    size_t off = (((size_t)b * NCH + c) * DN + d) * 16 + n;
    float hl = hbuf[off];
    float P = __expf(A * Sbuf[((size_t)b * NCH + c) * DN + d]);
    hbuf[off] = h;                 // now holds h_start for chunk c
    h = hl + P * h;
  }
}

// ---------------- scan phase 3: re-scan with h_start, D skip + SiLU(z) gate, y over u ------
__global__ __launch_bounds__(256) void scan_part2(const u16* u_g,
    const u16* __restrict__ xz, const float* __restrict__ xbc,
    const float* __restrict__ W_dt, const float* __restrict__ b_dt,
    const float* __restrict__ log_A, const float* __restrict__ D_param,
    const float* __restrict__ hbuf, u16* y) {
  int d0 = blockIdx.x * 256;
  int c  = blockIdx.y;
  int b  = blockIdx.z;
  int tid = threadIdx.x;
  int w = tid >> 6, l = tid & 63;
  int d = d0 + tid;
  __shared__ __align__(16) char smem[36864];
  u16* wdtb = (u16*)smem;                              // [0,32K) one-time
  u16 (*u_s)[256] = (u16(*)[256])smem;                 // [0,8K)
  u16 (*z_s)[256] = (u16(*)[256])(smem + 8192);        // [8K,16K)
  u16* dl_s = (u16*)(smem + 16384);                    // [16K,18K)
  float (*dt_s)[256] = (float(*)[256])(smem + 18432);  // [18K,34K)
  float (*bc_s)[32] = (float(*)[32])(smem + 34816);    // [34K,36K)

  for (int it = tid; it < 4096; it += 256) {
    int row = it >> 4, c4 = it & 15;
    float4 v = *(const float4*)(W_dt + (size_t)(d0 + row) * 64 + c4 * 4);
    ushort4_t o; o[0] = f2bf(v.x); o[1] = f2bf(v.y); o[2] = f2bf(v.z); o[3] = f2bf(v.w);
    *(ushort4_t*)((char*)wdtb + row * 128 + ((c4 * 8) ^ ((row & 7) << 4))) = o;
  }
  __syncthreads();
  bf16x8 wf[4][2];
  float bvals[4];
#pragma unroll
  for (int n = 0; n < 4; n++) {
    int row = w * 64 + n * 16 + (l & 15);
    bvals[n] = b_dt[d0 + row];
#pragma unroll
    for (int kk = 0; kk < 2; kk++) {
      int cb = (kk * 64 + ((l >> 4) << 4)) ^ ((row & 7) << 4);
      wf[n][kk] = *(const bf16x8*)((const char*)wdtb + row * 128 + cb);
    }
  }
  __syncthreads();

  float A2[16];
#pragma unroll
  for (int n = 0; n < 16; n++)
    A2[n] = -__expf(log_A[(size_t)d * 16 + n]) * 1.44269504f;
  float Dp = D_param[d];
  float h[16];
  const float* hp = hbuf + ((((size_t)b * NCH + c) * DN) + d) * 16;
#pragma unroll
  for (int n = 0; n < 16; n++) h[n] = hp[n];
  size_t t0 = (size_t)b * TT + (size_t)c * CHL;
  for (int wnd = 0; wnd < CHL / SW; wnd++) {
    size_t i0 = t0 + (size_t)wnd * SW;
#pragma unroll
    for (int lq = 0; lq < 2; lq++) {
      int idx = tid + lq * 256;
      int tt = idx >> 5, q = (idx & 31) * 8;
      *(ushort8_t*)&u_s[tt][q] = *(const ushort8_t*)(u_g + (i0 + tt) * 2048 + d0 + q);
      *(ushort8_t*)&z_s[tt][q] = *(const ushort8_t*)(xz + (i0 + tt) * 4096 + 2048 + d0 + q);
    }
    {
      int row = tid >> 4, c4 = tid & 15;
      float4 v = *(const float4*)(xbc + (i0 + row) * XBCS + c4 * 4);
      ushort4_t o; o[0] = f2bf(v.x); o[1] = f2bf(v.y); o[2] = f2bf(v.z); o[3] = f2bf(v.w);
      *(ushort4_t*)((char*)dl_s + row * 128 + ((c4 * 8) ^ ((row & 7) << 4))) = o;
      bc_s[row][c4] = xbc[(i0 + row) * XBCS + 64 + c4];
      bc_s[row][16 + c4] = xbc[(i0 + row) * XBCS + 80 + c4];
    }
    __syncthreads();
    f32x4 dacc[4] = {};
    bf16x8 afr[2];
#pragma unroll
    for (int kk = 0; kk < 2; kk++) {
      int row = l & 15;
      int cb = (kk * 64 + ((l >> 4) << 4)) ^ ((row & 7) << 4);
      afr[kk] = *(const bf16x8*)((const char*)dl_s + row * 128 + cb);
    }
#pragma unroll
    for (int n = 0; n < 4; n++)
#pragma unroll
      for (int kk = 0; kk < 2; kk++)
        dacc[n] = __builtin_amdgcn_mfma_f32_16x16x32_bf16(afr[kk], wf[n][kk], dacc[n], 0, 0, 0);
#pragma unroll
    for (int n = 0; n < 4; n++) {
      int dcol = w * 64 + n * 16 + (l & 15);
#pragma unroll
      for (int r = 0; r < 4; r++) {
        float s = dacc[n][r] + bvals[n];
        float sp = (s > 20.f) ? s : log1pf(__expf(s));
        dt_s[(l >> 4) * 4 + r][dcol] = fminf(fmaxf(sp + 1e-3f, 1e-3f), 0.1f);
      }
    }
    __syncthreads();
    for (int tt = 0; tt < SW; tt++) {
      float dtv = dt_s[tt][tid];
      float uv = bf2f(u_s[tt][tid]), zv = bf2f(z_s[tt][tid]);
      float xin = dtv * uv;
      float yv = 0.f;
#pragma unroll
      for (int n = 0; n < 16; n++) {
        h[n] = exp2f(dtv * A2[n]) * h[n] + xin * bc_s[tt][n];
        yv += h[n] * bc_s[tt][16 + n];
      }
      yv += uv * Dp;
      yv *= zv / (1.f + __expf(-zv));
      y[(i0 + tt) * 2048 + d] = f2bf(yv);
    }
    __syncthreads();
  }
}

extern "C" void kernel_launch(void* const* d_in, const int* in_sizes, int n_in,
                              void* d_out, int out_size, void* d_ws, size_t ws_size,
                              hipStream_t stream) {
  const float* x       = (const float*)d_in[0];
  const float* W_in    = (const float*)d_in[1];
  const float* conv_w  = (const float*)d_in[2];
  const float* conv_b  = (const float*)d_in[3];
  const float* W_x     = (const float*)d_in[4];
  const float* W_dt    = (const float*)d_in[5];
  const float* b_dt    = (const float*)d_in[6];
  const float* log_A   = (const float*)d_in[7];
  const float* D_param = (const float*)d_in[8];
  const float* W_out   = (const float*)d_in[9];
  const float* ln_w    = (const float*)d_in[10];
  const float* ln_b    = (const float*)d_in[11];
  float* out = (float*)d_out;

  // ws (proven >=198MiB): xz 128MiB + u 64MiB + 6MiB tail (W_out bf16 staging)
  size_t need = (size_t)MROWS * 4096 * 2 + (size_t)MROWS * DN * 2 + (size_t)MROWS * 96 * 4;
  if (ws_size < need) return;
  u16*   xz  = (u16*)d_ws;                        // 16384 x 4096 bf16 (x_inner | z)
  u16*   u   = xz + (size_t)MROWS * 4096;         // 16384 x 2048 bf16 (y overwrites in place)
  u16*   W_out_b = (u16*)(u + (size_t)MROWS * DN);// 4MiB, used only for gemm2 staging

  // d_out (64MiB) staging: all dead before gemm2 fully overwrites d_out
  u16*   xn_b    = (u16*)d_out;                                  // [0,32)MiB, dead after gemm1
  float* xbc     = (float*)d_out;                                // [0,8)MiB, written AFTER gemm1
  u16*   W_in_b  = (u16*)((char*)d_out + (32u << 20));           // [32,40)MiB
  float* hbuf    = (float*)((char*)d_out + (40u << 20));         // [40,56)MiB (4*32*2048*16 f32)
  float* Sbuf    = (float*)((char*)d_out + (56u << 20));         // [56,57)MiB
  u16*   W_x_b   = (u16*)((char*)d_out + (57u << 20));           // [57,57.5)MiB, 128x2048 bf16

  cvt_wx_kernel<<<(128 * 2048 / 4) / 256, 256, 0, stream>>>(W_x, W_x_b);
  ln_kernel<<<MROWS, 256, 0, stream>>>(x, ln_w, ln_b, xn_b);
  cvt_bf16_kernel<<<(4096 * 1024 / 4) / 256, 256, 0, stream>>>(W_in, W_in_b, 4096 * 1024 / 4);
  gemm_mfma_nt<true, false><<<dim3(MROWS / 128, 4096 / 128), 256, 0, stream>>>(
      xn_b, DM, W_in_b, DM, xz, 4096, nullptr, DM);
  conv_silu_kernel<<<MROWS, 256, 0, stream>>>(xz, conv_w, conv_b, u);
  // xbc = u @ W_x.T via MFMA (N padded 96->128, pad cols are zeros); overwrites dead xn_b
  gemm_mfma_nt<false, false><<<dim3(MROWS / 128, XBCS / 128), 256, 0, stream>>>(
      u, DN, W_x_b, DN, xbc, XBCS, nullptr, DN);
  scan_part1<<<dim3(DN / 256, NCH, 4), 256, 0, stream>>>(
      u, xbc, W_dt, b_dt, log_A, hbuf, Sbuf);
  scan_combine<<<4 * DN * 16 / 256, 256, 0, stream>>>(log_A, Sbuf, hbuf);
  scan_part2<<<dim3(DN / 256, NCH, 4), 256, 0, stream>>>(
      u, xz, xbc, W_dt, b_dt, log_A, D_param, hbuf, u);
  cvt_bf16_kernel<<<(1024 * 2048 / 4) / 256, 256, 0, stream>>>(W_out, W_out_b, 1024 * 2048 / 4);
  gemm_mfma_nt<false, true><<<dim3(MROWS / 128, 1024 / 128), 256, 0, stream>>>(
      u, DN, W_out_b, DN, out, DM, x, DN);
}

// Round 3
// 936.921 us; speedup vs baseline: 2.5561x; 1.0464x over previous
//
#include <hip/hip_runtime.h>
#include <cstdint>
#include <cstddef>

#define TT 4096
#define DM 1024
#define DN 2048
#define MROWS 16384  // B*T
#define NCH 64       // scan chunks per sequence
#define CHL 64       // chunk length (TT/NCH)
#define SW 16        // LDS staging window inside a chunk
#define XBCS 128     // xbc row stride (f32), padded from 96 for MFMA GEMM

typedef unsigned short u16;
typedef u16 ushort8_t __attribute__((ext_vector_type(8)));
typedef u16 ushort4_t __attribute__((ext_vector_type(4)));
typedef short bf16x8 __attribute__((ext_vector_type(8)));   // MFMA A/B frag (4 VGPR)
typedef float f32x4 __attribute__((ext_vector_type(4)));    // MFMA C/D frag

__device__ __forceinline__ float bf2f(u16 b) {
  return __uint_as_float(((unsigned int)b) << 16);
}
__device__ __forceinline__ u16 f2bf(float f) {
  unsigned int u = __float_as_uint(f);
  u = u + 0x7FFFu + ((u >> 16) & 1u);   // round-to-nearest-even
  return (u16)(u >> 16);
}
__device__ __forceinline__ u16 f2h(float f) {
  _Float16 h = (_Float16)f;
  return __builtin_bit_cast(u16, h);
}
__device__ __forceinline__ float h2f(u16 v) {
  return (float)__builtin_bit_cast(_Float16, v);
}

__device__ __forceinline__ void gload_lds16(const void* g, void* l) {
  __builtin_amdgcn_global_load_lds(
      (const __attribute__((address_space(1))) unsigned int*)g,
      (__attribute__((address_space(3))) unsigned int*)l, 16, 0, 0);
}

// ---------------- f32 -> bf16 converter (weights) ----------------
__global__ __launch_bounds__(256) void cvt_bf16_kernel(const float* __restrict__ in,
    u16* __restrict__ out, int n4) {
  int i = blockIdx.x * 256 + threadIdx.x;
  if (i >= n4) return;
  float4 v = ((const float4*)in)[i];
  ushort4_t o; o[0] = f2bf(v.x); o[1] = f2bf(v.y); o[2] = f2bf(v.z); o[3] = f2bf(v.w);
  ((ushort4_t*)out)[i] = o;
}

// ---------------- W_x f32(96x2048) -> bf16(128x2048), rows 96..127 zero ----------------
__global__ __launch_bounds__(256) void cvt_wx_kernel(const float* __restrict__ W_x,
    u16* __restrict__ out) {
  int i = blockIdx.x * 256 + threadIdx.x;   // over 128*2048/4 = 65536 float4 slots
  int row = i >> 9;                         // 512 float4 per row
  ushort4_t o;
  if (row < 96) {
    float4 v = ((const float4*)W_x)[i];
    o[0] = f2bf(v.x); o[1] = f2bf(v.y); o[2] = f2bf(v.z); o[3] = f2bf(v.w);
  } else {
    o[0] = 0; o[1] = 0; o[2] = 0; o[3] = 0;
  }
  ((ushort4_t*)out)[i] = o;
}

// ---------------- LayerNorm -> bf16 out ----------------
__global__ __launch_bounds__(256) void ln_kernel(const float* __restrict__ x,
    const float* __restrict__ ln_w, const float* __restrict__ ln_b,
    u16* __restrict__ xn) {
  int row = blockIdx.x;
  int tid = threadIdx.x;
  const float4* xr = (const float4*)(x + (size_t)row * DM);
  float4 v = xr[tid];
  float s  = v.x + v.y + v.z + v.w;
  float s2 = v.x*v.x + v.y*v.y + v.z*v.z + v.w*v.w;
#pragma unroll
  for (int o = 32; o > 0; o >>= 1) { s += __shfl_down(s, o, 64); s2 += __shfl_down(s2, o, 64); }
  __shared__ float red[2][4];
  __shared__ float mv[2];
  int wid = tid >> 6, lane = tid & 63;
  if (lane == 0) { red[0][wid] = s; red[1][wid] = s2; }
  __syncthreads();
  if (tid == 0) {
    float a  = red[0][0] + red[0][1] + red[0][2] + red[0][3];
    float b2 = red[1][0] + red[1][1] + red[1][2] + red[1][3];
    float mean = a * (1.f / DM);
    float var  = b2 * (1.f / DM) - mean * mean;
    mv[0] = mean; mv[1] = rsqrtf(var + 1e-5f);
  }
  __syncthreads();
  float mean = mv[0], inv = mv[1];
  float4 w = ((const float4*)ln_w)[tid];
  float4 b = ((const float4*)ln_b)[tid];
  ushort4_t o;
  o[0] = f2bf((v.x - mean) * inv * w.x + b.x);
  o[1] = f2bf((v.y - mean) * inv * w.y + b.y);
  o[2] = f2bf((v.z - mean) * inv * w.z + b.z);
  o[3] = f2bf((v.w - mean) * inv * w.w + b.w);
  *(ushort4_t*)(xn + (size_t)row * DM + tid * 4) = o;
}

// ---------------- bf16 MFMA GEMM, NT: C[i][j] = sum_k A[i][k]*B[j][k] -----------
// MODE 0: bf16 out. MODE 1: f32 out + bf16 dl copy of cols<64 (needs bj==0 grid).
// MODE 2: f32 out + residual add. MODE 3: f16 out = clamp(softplus(v+bias)+1e-3).
template<int MODE>
__global__ __launch_bounds__(256) void gemm_mfma_nt(
    const u16* __restrict__ A, int lda,
    const u16* __restrict__ B, int ldb,
    void* __restrict__ Cp, int ldc,
    const float* __restrict__ Res, int K,
    const float* __restrict__ bias, u16* __restrict__ dl_out) {
  __shared__ __align__(16) u16 a_s[128 * 64];
  __shared__ __align__(16) u16 b_s[128 * 64];
  const int tid = threadIdx.x;
  const int w = tid >> 6, l = tid & 63;
  const int wr = w >> 1, wc = w & 1;
  const int bi = blockIdx.x, bj = blockIdx.y;
  const int lrow = l >> 3;                    // lane's row-in-8 within a 1KB chunk
  const int scol = ((l & 7) ^ lrow) * 16;     // inverse-swizzled source byte-in-row

  f32x4 acc[4][4] = {};

  const u16* Abase = A + (size_t)(bi * 128 + w * 8 + lrow) * lda;
  const u16* Bbase = B + (size_t)(bj * 128 + w * 8 + lrow) * ldb;

  for (int k0 = 0; k0 < K; k0 += 64) {
#pragma unroll
    for (int c = 0; c < 4; c++) {
      const char* ga = (const char*)(Abase + (size_t)(c * 32) * lda + k0) + scol;
      const char* gb = (const char*)(Bbase + (size_t)(c * 32) * ldb + k0) + scol;
      gload_lds16(ga, (char*)a_s + c * 4096 + w * 1024);
      gload_lds16(gb, (char*)b_s + c * 4096 + w * 1024);
    }
    __syncthreads();
#pragma unroll
    for (int kk = 0; kk < 2; kk++) {
      bf16x8 af[4], bfr[4];
#pragma unroll
      for (int m = 0; m < 4; m++) {
        int fr = wr * 64 + m * 16 + (l & 15);
        int cb = (kk * 64 + ((l >> 4) << 4)) ^ ((fr & 7) << 4);
        af[m] = *(const bf16x8*)((const char*)a_s + fr * 128 + cb);
      }
#pragma unroll
      for (int n = 0; n < 4; n++) {
        int fr = wc * 64 + n * 16 + (l & 15);
        int cb = (kk * 64 + ((l >> 4) << 4)) ^ ((fr & 7) << 4);
        bfr[n] = *(const bf16x8*)((const char*)b_s + fr * 128 + cb);
      }
#pragma unroll
      for (int m = 0; m < 4; m++)
#pragma unroll
        for (int n = 0; n < 4; n++)
          acc[m][n] = __builtin_amdgcn_mfma_f32_16x16x32_bf16(af[m], bfr[n], acc[m][n], 0, 0, 0);
    }
    __syncthreads();
  }
  const int col0 = bj * 128 + wc * 64 + (l & 15);
  const int row0 = bi * 128 + wr * 64 + (l >> 4) * 4;
#pragma unroll
  for (int m = 0; m < 4; m++)
#pragma unroll
    for (int n = 0; n < 4; n++) {
      int col = col0 + n * 16;
      float bv = 0.f;
      if constexpr (MODE == 3) bv = bias[col];
#pragma unroll
      for (int r = 0; r < 4; r++) {
        size_t row = (size_t)(row0 + m * 16 + r);
        float v = acc[m][n][r];
        if constexpr (MODE == 0) {
          ((u16*)Cp)[row * ldc + col] = f2bf(v);
        } else if constexpr (MODE == 1) {
          ((float*)Cp)[row * ldc + col] = v;
          if (col < 64) dl_out[row * 64 + col] = f2bf(v);
        } else if constexpr (MODE == 2) {
          v += Res[row * ldc + col];
          ((float*)Cp)[row * ldc + col] = v;
        } else {
          float s = v + bv;
          float sp = (s > 20.f) ? s : log1pf(__expf(s));
          float dtv = fminf(fmaxf(sp + 1e-3f, 1e-3f), 0.1f);
          ((u16*)Cp)[row * ldc + col] = f2h(dtv);
        }
      }
    }
}

// ---------------- causal depthwise conv (width 4) + SiLU; bf16 in, bf16 out ----------------
__global__ __launch_bounds__(256) void conv_silu_kernel(const u16* __restrict__ xz,
    const float* __restrict__ conv_w, const float* __restrict__ conv_b,
    u16* __restrict__ u) {
  size_t gid = (size_t)blockIdx.x * 256 + threadIdx.x;
  int c = (int)(gid & 255);
  size_t i = gid >> 8;
  int t = (int)(i & (TT - 1));
  int d0 = c * 8;
  const u16* base = xz + i * 4096 + d0;
  ushort8_t r0 = *(const ushort8_t*)base;
  ushort8_t r1 = 0, r2 = 0, r3 = 0;
  if (t >= 1) r1 = *(const ushort8_t*)(base - 4096);
  if (t >= 2) r2 = *(const ushort8_t*)(base - 2 * 4096);
  if (t >= 3) r3 = *(const ushort8_t*)(base - 3 * 4096);
  float cbv[8];
  *(float4*)&cbv[0] = *(const float4*)(conv_b + d0);
  *(float4*)&cbv[4] = *(const float4*)(conv_b + d0 + 4);
  ushort8_t o;
#pragma unroll
  for (int j = 0; j < 8; j++) {
    float4 w = *(const float4*)(conv_w + (size_t)(d0 + j) * 4);
    float a = cbv[j] + w.w * bf2f(r0[j]) + w.z * bf2f(r1[j])
            + w.y * bf2f(r2[j]) + w.x * bf2f(r3[j]);
    a = a / (1.f + __expf(-a));
    o[j] = f2bf(a);
  }
  *(ushort8_t*)(u + i * 2048 + d0) = o;
}

// ---------------- scan phase 1: local chunk scan from h=0; writes y_local over u ----------
// y_local = C.h_local + u*D  (bf16, in-place over u); also h_end -> hbuf, sum(dt) -> Sbuf.
__global__ __launch_bounds__(256) void scan_part1(u16* u,
    const u16* __restrict__ dt_g, const float* __restrict__ xbc,
    const float* __restrict__ log_A, const float* __restrict__ D_param,
    float* __restrict__ hbuf, float* __restrict__ Sbuf) {
  int d0 = blockIdx.x * 256;
  int c  = blockIdx.y;
  int b  = blockIdx.z;
  int tid = threadIdx.x;
  int w = tid >> 6, l = tid & 63;
  int d = d0 + tid;
  __shared__ __align__(16) u16 u_s[SW][256];     // 8K
  __shared__ __align__(16) u16 dt_s[SW][256];    // 8K
  __shared__ __align__(16) float bc_s[SW][32];   // 2K (B | C)

  float A2[16];
#pragma unroll
  for (int n = 0; n < 4; n++) {
    float4 la = *(const float4*)(log_A + (size_t)d * 16 + n * 4);
    A2[n*4+0] = -__expf(la.x) * 1.44269504f;
    A2[n*4+1] = -__expf(la.y) * 1.44269504f;
    A2[n*4+2] = -__expf(la.z) * 1.44269504f;
    A2[n*4+3] = -__expf(la.w) * 1.44269504f;
  }
  float Dp = D_param[d];
  float h[16] = {};
  float sdt = 0.f;
  size_t t0 = (size_t)b * TT + (size_t)c * CHL;
  for (int wnd = 0; wnd < CHL / SW; wnd++) {
    size_t i0 = t0 + (size_t)wnd * SW;
    gload_lds16(u    + (i0 + 2*w     + (l >> 5)) * 2048 + d0 + (l & 31) * 8, (char*)u_s  + w * 1024);
    gload_lds16(u    + (i0 + 8 + 2*w + (l >> 5)) * 2048 + d0 + (l & 31) * 8, (char*)u_s  + 4096 + w * 1024);
    gload_lds16(dt_g + (i0 + 2*w     + (l >> 5)) * 4096 + d0 + (l & 31) * 8, (char*)dt_s + w * 1024);
    gload_lds16(dt_g + (i0 + 8 + 2*w + (l >> 5)) * 4096 + d0 + (l & 31) * 8, (char*)dt_s + 4096 + w * 1024);
    {
      int r2 = tid >> 4, q2 = (tid & 15) * 2;
      *(float2*)&bc_s[r2][q2] = *(const float2*)(xbc + (i0 + r2) * XBCS + 64 + q2);
    }
    __syncthreads();
    for (int tt = 0; tt < SW; tt++) {
      float dtv = h2f(dt_s[tt][tid]);
      sdt += dtv;
      float uv = bf2f(u_s[tt][tid]);
      float xin = dtv * uv;
      float yv = uv * Dp;
      const float* Bp = bc_s[tt];
#pragma unroll
      for (int n = 0; n < 16; n++) {
        h[n] = exp2f(dtv * A2[n]) * h[n] + xin * Bp[n];
        yv += h[n] * Bp[16 + n];
      }
      u[(i0 + tt) * 2048 + d] = f2bf(yv);   // y_local over dead u (staged already)
    }
    __syncthreads();
  }
  float* hp = hbuf + ((((size_t)b * NCH + c) * DN) + d) * 16;
#pragma unroll
  for (int n = 0; n < 16; n++) hp[n] = h[n];
  Sbuf[((size_t)b * NCH + c) * DN + d] = sdt;
}

// ---------------- scan phase 2: sequential chunk combine (in-place h_end -> h_start) -------
__global__ __launch_bounds__(256) void scan_combine(const float* __restrict__ log_A,
    const float* __restrict__ Sbuf, float* __restrict__ hbuf) {
  int idx = blockIdx.x * 256 + threadIdx.x;    // over B*DN*16
  int n = idx & 15, d = (idx >> 4) & (DN - 1), b = idx >> 15;
  float A = -__expf(log_A[(size_t)d * 16 + n]);
  float h = 0.f;
#pragma unroll
  for (int c = 0; c < NCH; c++) {
    size_t off = (((size_t)b * NCH + c) * DN + d) * 16 + n;
    float hl = hbuf[off];
    float P = __expf(A * Sbuf[((size_t)b * NCH + c) * DN + d]);
    hbuf[off] = h;                 // now holds h_start for chunk c
    h = hl + P * h;
  }
}

// ---------------- scan phase 3: y = (y_local + C.(exp(A*cum) o h_start)) * silu(z) --------
__global__ __launch_bounds__(256) void scan_part2(u16* yl,
    const u16* __restrict__ xz, const float* __restrict__ xbc,
    const u16* __restrict__ dt_g, const float* __restrict__ log_A,
    const float* __restrict__ hbuf) {
  int d0 = blockIdx.x * 256;
  int c  = blockIdx.y;
  int b  = blockIdx.z;
  int tid = threadIdx.x;
  int w = tid >> 6, l = tid & 63;
  int d = d0 + tid;
  __shared__ __align__(16) u16 yl_s[SW][256];    // 8K
  __shared__ __align__(16) u16 z_s[SW][256];     // 8K
  __shared__ __align__(16) u16 dt_s[SW][256];    // 8K
  __shared__ __align__(16) float c_s[SW][16];    // 1K

  float A2[16];
#pragma unroll
  for (int n = 0; n < 4; n++) {
    float4 la = *(const float4*)(log_A + (size_t)d * 16 + n * 4);
    A2[n*4+0] = -__expf(la.x) * 1.44269504f;
    A2[n*4+1] = -__expf(la.y) * 1.44269504f;
    A2[n*4+2] = -__expf(la.z) * 1.44269504f;
    A2[n*4+3] = -__expf(la.w) * 1.44269504f;
  }
  float hs[16];
  const float* hp = hbuf + ((((size_t)b * NCH + c) * DN) + d) * 16;
#pragma unroll
  for (int n = 0; n < 16; n++) hs[n] = hp[n];
  float cum = 0.f;
  size_t t0 = (size_t)b * TT + (size_t)c * CHL;
  for (int wnd = 0; wnd < CHL / SW; wnd++) {
    size_t i0 = t0 + (size_t)wnd * SW;
    gload_lds16(yl   + (i0 + 2*w     + (l >> 5)) * 2048 + d0 + (l & 31) * 8, (char*)yl_s + w * 1024);
    gload_lds16(yl   + (i0 + 8 + 2*w + (l >> 5)) * 2048 + d0 + (l & 31) * 8, (char*)yl_s + 4096 + w * 1024);
    gload_lds16(xz   + (i0 + 2*w     + (l >> 5)) * 4096 + 2048 + d0 + (l & 31) * 8, (char*)z_s + w * 1024);
    gload_lds16(xz   + (i0 + 8 + 2*w + (l >> 5)) * 4096 + 2048 + d0 + (l & 31) * 8, (char*)z_s + 4096 + w * 1024);
    gload_lds16(dt_g + (i0 + 2*w     + (l >> 5)) * 4096 + d0 + (l & 31) * 8, (char*)dt_s + w * 1024);
    gload_lds16(dt_g + (i0 + 8 + 2*w + (l >> 5)) * 4096 + d0 + (l & 31) * 8, (char*)dt_s + 4096 + w * 1024);
    if (tid < SW * 16) {
      int r2 = tid >> 4, q2 = tid & 15;
      c_s[r2][q2] = xbc[(i0 + r2) * XBCS + 80 + q2];
    }
    __syncthreads();
    for (int tt = 0; tt < SW; tt++) {
      float dtv = h2f(dt_s[tt][tid]);
      cum += dtv;
      float yv = bf2f(yl_s[tt][tid]);
      float zv = bf2f(z_s[tt][tid]);
      const float* Cr = c_s[tt];
#pragma unroll
      for (int n = 0; n < 16; n++)
        yv += Cr[n] * (exp2f(cum * A2[n]) * hs[n]);
      yv *= zv / (1.f + __expf(-zv));
      yl[(i0 + tt) * 2048 + d] = f2bf(yv);   // final y over y_local (staged already)
    }
    __syncthreads();
  }
}

extern "C" void kernel_launch(void* const* d_in, const int* in_sizes, int n_in,
                              void* d_out, int out_size, void* d_ws, size_t ws_size,
                              hipStream_t stream) {
  const float* x       = (const float*)d_in[0];
  const float* W_in    = (const float*)d_in[1];
  const float* conv_w  = (const float*)d_in[2];
  const float* conv_b  = (const float*)d_in[3];
  const float* W_x     = (const float*)d_in[4];
  const float* W_dt    = (const float*)d_in[5];
  const float* b_dt    = (const float*)d_in[6];
  const float* log_A   = (const float*)d_in[7];
  const float* D_param = (const float*)d_in[8];
  const float* W_out   = (const float*)d_in[9];
  const float* ln_w    = (const float*)d_in[10];
  const float* ln_b    = (const float*)d_in[11];
  float* out = (float*)d_out;

  // ws (proven >=198MiB): xz 128MiB + u 64MiB + 6MiB tail (W_out bf16 staging)
  size_t need = (size_t)MROWS * 4096 * 2 + (size_t)MROWS * DN * 2 + (size_t)MROWS * 96 * 4;
  if (ws_size < need) return;
  u16*   xz  = (u16*)d_ws;                        // 16384 x 4096 bf16 (x_inner | z); x_inner
                                                  // cols become f16 dt after dt_gemm
  u16*   u   = xz + (size_t)MROWS * 4096;         // 16384 x 2048 bf16 (u -> y_local -> y)
  u16*   W_out_b = (u16*)(u + (size_t)MROWS * DN);// 4MiB, used only for gemm2 staging

  // d_out (64MiB) staging: all dead before gemm2 fully overwrites d_out
  u16*   xn_b    = (u16*)d_out;                                  // [0,32)MiB, dead after gemm1
  float* xbc     = (float*)d_out;                                // [0,8)MiB, written AFTER gemm1
  float* hbuf    = (float*)((char*)d_out + (8u << 20));          // [8,40)MiB (4*64*2048*16 f32)
  u16*   W_in_b  = (u16*)((char*)d_out + (40u << 20));           // [40,48)MiB
  float* Sbuf    = (float*)((char*)d_out + (48u << 20));         // [48,50)MiB
  u16*   W_x_b   = (u16*)((char*)d_out + (50u << 20));           // [50,50.5)MiB
  u16*   W_dt_b  = (u16*)((char*)d_out + (50u << 20) + (512u << 10)); // [50.5,50.75) 2048x64 bf16
  u16*   dl_b    = (u16*)((char*)d_out + (51u << 20));           // [51,53)MiB 16384x64 bf16

  cvt_wx_kernel<<<(128 * 2048 / 4) / 256, 256, 0, stream>>>(W_x, W_x_b);
  cvt_bf16_kernel<<<(2048 * 64 / 4) / 256, 256, 0, stream>>>(W_dt, W_dt_b, 2048 * 64 / 4);
  ln_kernel<<<MROWS, 256, 0, stream>>>(x, ln_w, ln_b, xn_b);
  cvt_bf16_kernel<<<(4096 * 1024 / 4) / 256, 256, 0, stream>>>(W_in, W_in_b, 4096 * 1024 / 4);
  gemm_mfma_nt<0><<<dim3(MROWS / 128, 4096 / 128), 256, 0, stream>>>(
      xn_b, DM, W_in_b, DM, xz, 4096, nullptr, DM, nullptr, nullptr);
  conv_silu_kernel<<<MROWS, 256, 0, stream>>>(xz, conv_w, conv_b, u);
  // xbc = u @ W_x.T via MFMA (N padded 96->128); also emits dl bf16; overwrites dead xn_b
  gemm_mfma_nt<1><<<dim3(MROWS / 128, XBCS / 128), 256, 0, stream>>>(
      u, DN, W_x_b, DN, xbc, XBCS, nullptr, DN, nullptr, dl_b);
  // dt = clamp(softplus(dl @ W_dt.T + b_dt)+1e-3) -> f16 into dead x_inner cols of xz
  gemm_mfma_nt<3><<<dim3(MROWS / 128, DN / 128), 256, 0, stream>>>(
      dl_b, 64, W_dt_b, 64, xz, 4096, nullptr, 64, b_dt, nullptr);
  scan_part1<<<dim3(DN / 256, NCH, 4), 256, 0, stream>>>(
      u, xz, xbc, log_A, D_param, hbuf, Sbuf);
  scan_combine<<<4 * DN * 16 / 256, 256, 0, stream>>>(log_A, Sbuf, hbuf);
  scan_part2<<<dim3(DN / 256, NCH, 4), 256, 0, stream>>>(
      u, xz, xbc, xz, log_A, hbuf);
  cvt_bf16_kernel<<<(1024 * 2048 / 4) / 256, 256, 0, stream>>>(W_out, W_out_b, 1024 * 2048 / 4);
  gemm_mfma_nt<2><<<dim3(MROWS / 128, 1024 / 128), 256, 0, stream>>>(
      u, DN, W_out_b, DN, out, DM, x, DN, nullptr, nullptr);
}

// Round 4
// 774.155 us; speedup vs baseline: 3.0936x; 1.2103x over previous
//
#include <hip/hip_runtime.h>
#include <cstdint>
#include <cstddef>

#define TT 4096
#define DM 1024
#define DN 2048
#define MROWS 16384  // B*T
#define NCH 64       // scan chunks per sequence
#define CHL 64       // chunk length (TT/NCH)
#define SW 16        // LDS staging window inside a chunk
#define XBCS 128     // xbc row stride (f32), padded from 96 for MFMA GEMM

typedef unsigned short u16;
typedef u16 ushort8_t __attribute__((ext_vector_type(8)));
typedef u16 ushort4_t __attribute__((ext_vector_type(4)));
typedef short bf16x8 __attribute__((ext_vector_type(8)));   // MFMA A/B frag (4 VGPR)
typedef float f32x4 __attribute__((ext_vector_type(4)));    // MFMA C/D frag

__device__ __forceinline__ float bf2f(u16 b) {
  return __uint_as_float(((unsigned int)b) << 16);
}
__device__ __forceinline__ u16 f2bf(float f) {
  unsigned int u = __float_as_uint(f);
  u = u + 0x7FFFu + ((u >> 16) & 1u);   // round-to-nearest-even
  return (u16)(u >> 16);
}
__device__ __forceinline__ u16 f2h(float f) {
  _Float16 h = (_Float16)f;
  return __builtin_bit_cast(u16, h);
}
__device__ __forceinline__ float h2f(u16 v) {
  return (float)__builtin_bit_cast(_Float16, v);
}

__device__ __forceinline__ void gload_lds16(const void* g, void* l) {
  __builtin_amdgcn_global_load_lds(
      (const __attribute__((address_space(1))) unsigned int*)g,
      (__attribute__((address_space(3))) unsigned int*)l, 16, 0, 0);
}

// ---------------- f32 -> bf16 converter (weights) ----------------
__global__ __launch_bounds__(256) void cvt_bf16_kernel(const float* __restrict__ in,
    u16* __restrict__ out, int n4) {
  int i = blockIdx.x * 256 + threadIdx.x;
  if (i >= n4) return;
  float4 v = ((const float4*)in)[i];
  ushort4_t o; o[0] = f2bf(v.x); o[1] = f2bf(v.y); o[2] = f2bf(v.z); o[3] = f2bf(v.w);
  ((ushort4_t*)out)[i] = o;
}

// ---------------- W_x f32(96x2048) -> bf16(128x2048), rows 96..127 zero ----------------
__global__ __launch_bounds__(256) void cvt_wx_kernel(const float* __restrict__ W_x,
    u16* __restrict__ out) {
  int i = blockIdx.x * 256 + threadIdx.x;   // over 128*2048/4 = 65536 float4 slots
  int row = i >> 9;                         // 512 float4 per row
  ushort4_t o;
  if (row < 96) {
    float4 v = ((const float4*)W_x)[i];
    o[0] = f2bf(v.x); o[1] = f2bf(v.y); o[2] = f2bf(v.z); o[3] = f2bf(v.w);
  } else {
    o[0] = 0; o[1] = 0; o[2] = 0; o[3] = 0;
  }
  ((ushort4_t*)out)[i] = o;
}

// ---------------- LayerNorm -> bf16 out ----------------
__global__ __launch_bounds__(256) void ln_kernel(const float* __restrict__ x,
    const float* __restrict__ ln_w, const float* __restrict__ ln_b,
    u16* __restrict__ xn) {
  int row = blockIdx.x;
  int tid = threadIdx.x;
  const float4* xr = (const float4*)(x + (size_t)row * DM);
  float4 v = xr[tid];
  float s  = v.x + v.y + v.z + v.w;
  float s2 = v.x*v.x + v.y*v.y + v.z*v.z + v.w*v.w;
#pragma unroll
  for (int o = 32; o > 0; o >>= 1) { s += __shfl_down(s, o, 64); s2 += __shfl_down(s2, o, 64); }
  __shared__ float red[2][4];
  __shared__ float mv[2];
  int wid = tid >> 6, lane = tid & 63;
  if (lane == 0) { red[0][wid] = s; red[1][wid] = s2; }
  __syncthreads();
  if (tid == 0) {
    float a  = red[0][0] + red[0][1] + red[0][2] + red[0][3];
    float b2 = red[1][0] + red[1][1] + red[1][2] + red[1][3];
    float mean = a * (1.f / DM);
    float var  = b2 * (1.f / DM) - mean * mean;
    mv[0] = mean; mv[1] = rsqrtf(var + 1e-5f);
  }
  __syncthreads();
  float mean = mv[0], inv = mv[1];
  float4 w = ((const float4*)ln_w)[tid];
  float4 b = ((const float4*)ln_b)[tid];
  ushort4_t o;
  o[0] = f2bf((v.x - mean) * inv * w.x + b.x);
  o[1] = f2bf((v.y - mean) * inv * w.y + b.y);
  o[2] = f2bf((v.z - mean) * inv * w.z + b.z);
  o[3] = f2bf((v.w - mean) * inv * w.w + b.w);
  *(ushort4_t*)(xn + (size_t)row * DM + tid * 4) = o;
}

// ---------------- bf16 MFMA GEMM, NT: C[i][j] = sum_k A[i][k]*B[j][k] -----------
// MODE 0: bf16 out. MODE 1: f32 out + bf16 dl copy of cols<64 (needs bj==0 grid).
// MODE 2: f32 out + residual add. MODE 3: f16 out = clamp(softplus(v+bias)+1e-3).
template<int MODE>
__global__ __launch_bounds__(256) void gemm_mfma_nt(
    const u16* __restrict__ A, int lda,
    const u16* __restrict__ B, int ldb,
    void* __restrict__ Cp, int ldc,
    const float* __restrict__ Res, int K,
    const float* __restrict__ bias, u16* __restrict__ dl_out) {
  __shared__ __align__(16) u16 a_s[128 * 64];
  __shared__ __align__(16) u16 b_s[128 * 64];
  const int tid = threadIdx.x;
  const int w = tid >> 6, l = tid & 63;
  const int wr = w >> 1, wc = w & 1;
  const int bi = blockIdx.x, bj = blockIdx.y;
  const int lrow = l >> 3;                    // lane's row-in-8 within a 1KB chunk
  const int scol = ((l & 7) ^ lrow) * 16;     // inverse-swizzled source byte-in-row

  f32x4 acc[4][4] = {};

  const u16* Abase = A + (size_t)(bi * 128 + w * 8 + lrow) * lda;
  const u16* Bbase = B + (size_t)(bj * 128 + w * 8 + lrow) * ldb;

  for (int k0 = 0; k0 < K; k0 += 64) {
#pragma unroll
    for (int c = 0; c < 4; c++) {
      const char* ga = (const char*)(Abase + (size_t)(c * 32) * lda + k0) + scol;
      const char* gb = (const char*)(Bbase + (size_t)(c * 32) * ldb + k0) + scol;
      gload_lds16(ga, (char*)a_s + c * 4096 + w * 1024);
      gload_lds16(gb, (char*)b_s + c * 4096 + w * 1024);
    }
    __syncthreads();
#pragma unroll
    for (int kk = 0; kk < 2; kk++) {
      bf16x8 af[4], bfr[4];
#pragma unroll
      for (int m = 0; m < 4; m++) {
        int fr = wr * 64 + m * 16 + (l & 15);
        int cb = (kk * 64 + ((l >> 4) << 4)) ^ ((fr & 7) << 4);
        af[m] = *(const bf16x8*)((const char*)a_s + fr * 128 + cb);
      }
#pragma unroll
      for (int n = 0; n < 4; n++) {
        int fr = wc * 64 + n * 16 + (l & 15);
        int cb = (kk * 64 + ((l >> 4) << 4)) ^ ((fr & 7) << 4);
        bfr[n] = *(const bf16x8*)((const char*)b_s + fr * 128 + cb);
      }
#pragma unroll
      for (int m = 0; m < 4; m++)
#pragma unroll
        for (int n = 0; n < 4; n++)
          acc[m][n] = __builtin_amdgcn_mfma_f32_16x16x32_bf16(af[m], bfr[n], acc[m][n], 0, 0, 0);
    }
    __syncthreads();
  }
  const int col0 = bj * 128 + wc * 64 + (l & 15);
  const int row0 = bi * 128 + wr * 64 + (l >> 4) * 4;
#pragma unroll
  for (int m = 0; m < 4; m++)
#pragma unroll
    for (int n = 0; n < 4; n++) {
      int col = col0 + n * 16;
      float bv = 0.f;
      if constexpr (MODE == 3) bv = bias[col];
#pragma unroll
      for (int r = 0; r < 4; r++) {
        size_t row = (size_t)(row0 + m * 16 + r);
        float v = acc[m][n][r];
        if constexpr (MODE == 0) {
          ((u16*)Cp)[row * ldc + col] = f2bf(v);
        } else if constexpr (MODE == 1) {
          ((float*)Cp)[row * ldc + col] = v;
          if (col < 64) dl_out[row * 64 + col] = f2bf(v);
        } else if constexpr (MODE == 2) {
          v += Res[row * ldc + col];
          ((float*)Cp)[row * ldc + col] = v;
        } else {
          // fast softplus: log1p(exp(s)) via HW trans; s->-inf => 0 (dt=1e-3),
          // s large => exp->inf => log->inf => fmin caps at 0.1. Abs err ~1e-7
          // in the unclamped region (s < -2.26), << f16 dt quantization.
          float s = v + bv;
          float sp = __logf(1.f + __expf(s));
          float dtv = fminf(sp + 1e-3f, 0.1f);
          ((u16*)Cp)[row * ldc + col] = f2h(dtv);
        }
      }
    }
}

// ---------------- causal depthwise conv (width 4) + SiLU; bf16 in, bf16 out ----------------
__global__ __launch_bounds__(256) void conv_silu_kernel(const u16* __restrict__ xz,
    const float* __restrict__ conv_w, const float* __restrict__ conv_b,
    u16* __restrict__ u) {
  size_t gid = (size_t)blockIdx.x * 256 + threadIdx.x;
  int c = (int)(gid & 255);
  size_t i = gid >> 8;
  int t = (int)(i & (TT - 1));
  int d0 = c * 8;
  const u16* base = xz + i * 4096 + d0;
  ushort8_t r0 = *(const ushort8_t*)base;
  ushort8_t r1 = 0, r2 = 0, r3 = 0;
  if (t >= 1) r1 = *(const ushort8_t*)(base - 4096);
  if (t >= 2) r2 = *(const ushort8_t*)(base - 2 * 4096);
  if (t >= 3) r3 = *(const ushort8_t*)(base - 3 * 4096);
  float cbv[8];
  *(float4*)&cbv[0] = *(const float4*)(conv_b + d0);
  *(float4*)&cbv[4] = *(const float4*)(conv_b + d0 + 4);
  ushort8_t o;
#pragma unroll
  for (int j = 0; j < 8; j++) {
    float4 w = *(const float4*)(conv_w + (size_t)(d0 + j) * 4);
    float a = cbv[j] + w.w * bf2f(r0[j]) + w.z * bf2f(r1[j])
            + w.y * bf2f(r2[j]) + w.x * bf2f(r3[j]);
    a = a / (1.f + __expf(-a));
    o[j] = f2bf(a);
  }
  *(ushort8_t*)(u + i * 2048 + d0) = o;
}

// ---------------- scan phase 1: local chunk scan from h=0; writes y_local over u ----------
// y_local = C.h_local + u*D  (bf16, in-place over u); also h_end -> hbuf, sum(dt) -> Sbuf.
__global__ __launch_bounds__(256) void scan_part1(u16* u,
    const u16* __restrict__ dt_g, const float* __restrict__ xbc,
    const float* __restrict__ log_A, const float* __restrict__ D_param,
    float* __restrict__ hbuf, float* __restrict__ Sbuf) {
  int d0 = blockIdx.x * 256;
  int c  = blockIdx.y;
  int b  = blockIdx.z;
  int tid = threadIdx.x;
  int w = tid >> 6, l = tid & 63;
  int d = d0 + tid;
  __shared__ __align__(16) u16 u_s[SW][256];     // 8K
  __shared__ __align__(16) u16 dt_s[SW][256];    // 8K
  __shared__ __align__(16) float bc_s[SW][32];   // 2K (B | C)

  float A2[16];
#pragma unroll
  for (int n = 0; n < 4; n++) {
    float4 la = *(const float4*)(log_A + (size_t)d * 16 + n * 4);
    A2[n*4+0] = -__expf(la.x) * 1.44269504f;
    A2[n*4+1] = -__expf(la.y) * 1.44269504f;
    A2[n*4+2] = -__expf(la.z) * 1.44269504f;
    A2[n*4+3] = -__expf(la.w) * 1.44269504f;
  }
  float Dp = D_param[d];
  float h[16] = {};
  float sdt = 0.f;
  size_t t0 = (size_t)b * TT + (size_t)c * CHL;
  for (int wnd = 0; wnd < CHL / SW; wnd++) {
    size_t i0 = t0 + (size_t)wnd * SW;
    gload_lds16(u    + (i0 + 2*w     + (l >> 5)) * 2048 + d0 + (l & 31) * 8, (char*)u_s  + w * 1024);
    gload_lds16(u    + (i0 + 8 + 2*w + (l >> 5)) * 2048 + d0 + (l & 31) * 8, (char*)u_s  + 4096 + w * 1024);
    gload_lds16(dt_g + (i0 + 2*w     + (l >> 5)) * 4096 + d0 + (l & 31) * 8, (char*)dt_s + w * 1024);
    gload_lds16(dt_g + (i0 + 8 + 2*w + (l >> 5)) * 4096 + d0 + (l & 31) * 8, (char*)dt_s + 4096 + w * 1024);
    {
      int r2 = tid >> 4, q2 = (tid & 15) * 2;
      *(float2*)&bc_s[r2][q2] = *(const float2*)(xbc + (i0 + r2) * XBCS + 64 + q2);
    }
    __syncthreads();
    for (int tt = 0; tt < SW; tt++) {
      float dtv = h2f(dt_s[tt][tid]);
      sdt += dtv;
      float uv = bf2f(u_s[tt][tid]);
      float xin = dtv * uv;
      float yv = uv * Dp;
      const float* Bp = bc_s[tt];
#pragma unroll
      for (int n = 0; n < 16; n++) {
        h[n] = exp2f(dtv * A2[n]) * h[n] + xin * Bp[n];
        yv += h[n] * Bp[16 + n];
      }
      u[(i0 + tt) * 2048 + d] = f2bf(yv);   // y_local over dead u (staged already)
    }
    __syncthreads();
  }
  float* hp = hbuf + ((((size_t)b * NCH + c) * DN) + d) * 16;
#pragma unroll
  for (int n = 0; n < 16; n++) hp[n] = h[n];
  Sbuf[((size_t)b * NCH + c) * DN + d] = sdt;
}

// ---------------- scan phase 2: sequential chunk combine (in-place h_end -> h_start) -------
__global__ __launch_bounds__(256) void scan_combine(const float* __restrict__ log_A,
    const float* __restrict__ Sbuf, float* __restrict__ hbuf) {
  int idx = blockIdx.x * 256 + threadIdx.x;    // over B*DN*16
  int n = idx & 15, d = (idx >> 4) & (DN - 1), b = idx >> 15;
  float A = -__expf(log_A[(size_t)d * 16 + n]);
  float h = 0.f;
#pragma unroll
  for (int c = 0; c < NCH; c++) {
    size_t off = (((size_t)b * NCH + c) * DN + d) * 16 + n;
    float hl = hbuf[off];
    float P = __expf(A * Sbuf[((size_t)b * NCH + c) * DN + d]);
    hbuf[off] = h;                 // now holds h_start for chunk c
    h = hl + P * h;
  }
}

// ---------------- scan phase 3: y = (y_local + C.(exp(A*cum) o h_start)) * silu(z) --------
__global__ __launch_bounds__(256) void scan_part2(u16* yl,
    const u16* __restrict__ xz, const float* __restrict__ xbc,
    const u16* __restrict__ dt_g, const float* __restrict__ log_A,
    const float* __restrict__ hbuf) {
  int d0 = blockIdx.x * 256;
  int c  = blockIdx.y;
  int b  = blockIdx.z;
  int tid = threadIdx.x;
  int w = tid >> 6, l = tid & 63;
  int d = d0 + tid;
  __shared__ __align__(16) u16 yl_s[SW][256];    // 8K
  __shared__ __align__(16) u16 z_s[SW][256];     // 8K
  __shared__ __align__(16) u16 dt_s[SW][256];    // 8K
  __shared__ __align__(16) float c_s[SW][16];    // 1K

  float A2[16];
#pragma unroll
  for (int n = 0; n < 4; n++) {
    float4 la = *(const float4*)(log_A + (size_t)d * 16 + n * 4);
    A2[n*4+0] = -__expf(la.x) * 1.44269504f;
    A2[n*4+1] = -__expf(la.y) * 1.44269504f;
    A2[n*4+2] = -__expf(la.z) * 1.44269504f;
    A2[n*4+3] = -__expf(la.w) * 1.44269504f;
  }
  float hs[16];
  const float* hp = hbuf + ((((size_t)b * NCH + c) * DN) + d) * 16;
#pragma unroll
  for (int n = 0; n < 16; n++) hs[n] = hp[n];
  float cum = 0.f;
  size_t t0 = (size_t)b * TT + (size_t)c * CHL;
  for (int wnd = 0; wnd < CHL / SW; wnd++) {
    size_t i0 = t0 + (size_t)wnd * SW;
    gload_lds16(yl   + (i0 + 2*w     + (l >> 5)) * 2048 + d0 + (l & 31) * 8, (char*)yl_s + w * 1024);
    gload_lds16(yl   + (i0 + 8 + 2*w + (l >> 5)) * 2048 + d0 + (l & 31) * 8, (char*)yl_s + 4096 + w * 1024);
    gload_lds16(xz   + (i0 + 2*w     + (l >> 5)) * 4096 + 2048 + d0 + (l & 31) * 8, (char*)z_s + w * 1024);
    gload_lds16(xz   + (i0 + 8 + 2*w + (l >> 5)) * 4096 + 2048 + d0 + (l & 31) * 8, (char*)z_s + 4096 + w * 1024);
    gload_lds16(dt_g + (i0 + 2*w     + (l >> 5)) * 4096 + d0 + (l & 31) * 8, (char*)dt_s + w * 1024);
    gload_lds16(dt_g + (i0 + 8 + 2*w + (l >> 5)) * 4096 + d0 + (l & 31) * 8, (char*)dt_s + 4096 + w * 1024);
    if (tid < SW * 16) {
      int r2 = tid >> 4, q2 = tid & 15;
      c_s[r2][q2] = xbc[(i0 + r2) * XBCS + 80 + q2];
    }
    __syncthreads();
    for (int tt = 0; tt < SW; tt++) {
      float dtv = h2f(dt_s[tt][tid]);
      cum += dtv;
      float yv = bf2f(yl_s[tt][tid]);
      float zv = bf2f(z_s[tt][tid]);
      const float* Cr = c_s[tt];
#pragma unroll
      for (int n = 0; n < 16; n++)
        yv += Cr[n] * (exp2f(cum * A2[n]) * hs[n]);
      yv *= zv / (1.f + __expf(-zv));
      yl[(i0 + tt) * 2048 + d] = f2bf(yv);   // final y over y_local (staged already)
    }
    __syncthreads();
  }
}

extern "C" void kernel_launch(void* const* d_in, const int* in_sizes, int n_in,
                              void* d_out, int out_size, void* d_ws, size_t ws_size,
                              hipStream_t stream) {
  const float* x       = (const float*)d_in[0];
  const float* W_in    = (const float*)d_in[1];
  const float* conv_w  = (const float*)d_in[2];
  const float* conv_b  = (const float*)d_in[3];
  const float* W_x     = (const float*)d_in[4];
  const float* W_dt    = (const float*)d_in[5];
  const float* b_dt    = (const float*)d_in[6];
  const float* log_A   = (const float*)d_in[7];
  const float* D_param = (const float*)d_in[8];
  const float* W_out   = (const float*)d_in[9];
  const float* ln_w    = (const float*)d_in[10];
  const float* ln_b    = (const float*)d_in[11];
  float* out = (float*)d_out;

  // ws (proven >=198MiB): xz 128MiB + u 64MiB + 6MiB tail (W_out bf16 staging)
  size_t need = (size_t)MROWS * 4096 * 2 + (size_t)MROWS * DN * 2 + (size_t)MROWS * 96 * 4;
  if (ws_size < need) return;
  u16*   xz  = (u16*)d_ws;                        // 16384 x 4096 bf16 (x_inner | z); x_inner
                                                  // cols become f16 dt after dt_gemm
  u16*   u   = xz + (size_t)MROWS * 4096;         // 16384 x 2048 bf16 (u -> y_local -> y)
  u16*   W_out_b = (u16*)(u + (size_t)MROWS * DN);// 4MiB, used only for gemm2 staging

  // d_out (64MiB) staging: all dead before gemm2 fully overwrites d_out
  u16*   xn_b    = (u16*)d_out;                                  // [0,32)MiB, dead after gemm1
  float* xbc     = (float*)d_out;                                // [0,8)MiB, written AFTER gemm1
  float* hbuf    = (float*)((char*)d_out + (8u << 20));          // [8,40)MiB (4*64*2048*16 f32)
  u16*   W_in_b  = (u16*)((char*)d_out + (40u << 20));           // [40,48)MiB
  float* Sbuf    = (float*)((char*)d_out + (48u << 20));         // [48,50)MiB
  u16*   W_x_b   = (u16*)((char*)d_out + (50u << 20));           // [50,50.5)MiB
  u16*   W_dt_b  = (u16*)((char*)d_out + (50u << 20) + (512u << 10)); // [50.5,50.75) 2048x64 bf16
  u16*   dl_b    = (u16*)((char*)d_out + (51u << 20));           // [51,53)MiB 16384x64 bf16

  cvt_wx_kernel<<<(128 * 2048 / 4) / 256, 256, 0, stream>>>(W_x, W_x_b);
  cvt_bf16_kernel<<<(2048 * 64 / 4) / 256, 256, 0, stream>>>(W_dt, W_dt_b, 2048 * 64 / 4);
  ln_kernel<<<MROWS, 256, 0, stream>>>(x, ln_w, ln_b, xn_b);
  cvt_bf16_kernel<<<(4096 * 1024 / 4) / 256, 256, 0, stream>>>(W_in, W_in_b, 4096 * 1024 / 4);
  gemm_mfma_nt<0><<<dim3(MROWS / 128, 4096 / 128), 256, 0, stream>>>(
      xn_b, DM, W_in_b, DM, xz, 4096, nullptr, DM, nullptr, nullptr);
  conv_silu_kernel<<<MROWS, 256, 0, stream>>>(xz, conv_w, conv_b, u);
  // xbc = u @ W_x.T via MFMA (N padded 96->128); also emits dl bf16; overwrites dead xn_b
  gemm_mfma_nt<1><<<dim3(MROWS / 128, XBCS / 128), 256, 0, stream>>>(
      u, DN, W_x_b, DN, xbc, XBCS, nullptr, DN, nullptr, dl_b);
  // dt = clamp(softplus(dl @ W_dt.T + b_dt)+1e-3) -> f16 into dead x_inner cols of xz
  gemm_mfma_nt<3><<<dim3(MROWS / 128, DN / 128), 256, 0, stream>>>(
      dl_b, 64, W_dt_b, 64, xz, 4096, nullptr, 64, b_dt, nullptr);
  scan_part1<<<dim3(DN / 256, NCH, 4), 256, 0, stream>>>(
      u, xz, xbc, log_A, D_param, hbuf, Sbuf);
  scan_combine<<<4 * DN * 16 / 256, 256, 0, stream>>>(log_A, Sbuf, hbuf);
  scan_part2<<<dim3(DN / 256, NCH, 4), 256, 0, stream>>>(
      u, xz, xbc, xz, log_A, hbuf);
  cvt_bf16_kernel<<<(1024 * 2048 / 4) / 256, 256, 0, stream>>>(W_out, W_out_b, 1024 * 2048 / 4);
  gemm_mfma_nt<2><<<dim3(MROWS / 128, 1024 / 128), 256, 0, stream>>>(
      u, DN, W_out_b, DN, out, DM, x, DN, nullptr, nullptr);
}